// Round 3
// baseline (1416.607 us; speedup 1.0000x reference)
//
#include <hip/hip_runtime.h>

// AudioMamba forward. Inputs fp32 (auto-detected vs bf16 by detect_kernel ->
// mode flag in d_ws; all weight loads mode-branched). Output fp32.
// Intermediates fp32 in d_ws.
// Shapes: B=4, L=256 (8x32 patches), D_MODEL=512, D_INNER=1024, S=16, R=32.

#define BB 4
#define LL 256
#define DM 512
#define DI 1024

typedef unsigned short u16;
typedef unsigned int u32;

__device__ __forceinline__ float b2f(u16 u) {
  union { u32 i; float f; } v; v.i = ((u32)u) << 16; return v.f;
}
__device__ __forceinline__ void b2x2(u32 w, float& lo, float& hi) {
  union { u32 i; float f; } a, b;
  a.i = w << 16; b.i = w & 0xffff0000u;
  lo = a.f; hi = b.f;
}
__device__ __forceinline__ float silu_f(float x) { return x / (1.f + __expf(-x)); }

// ---- dtype-agnostic loads (mode: 1 = fp32 buffers, 0 = bf16) ----
__device__ __forceinline__ float ldone(const void* p, int i, int mode) {
  return mode ? ((const float*)p)[i] : b2f(((const u16*)p)[i]);
}
__device__ __forceinline__ void ld4(const void* p, int i, int mode, float* f) {
  if (mode) {
    float4 a = *(const float4*)((const float*)p + i);
    f[0] = a.x; f[1] = a.y; f[2] = a.z; f[3] = a.w;
  } else {
    ushort4 w = *(const ushort4*)((const u16*)p + i);
    f[0] = b2f(w.x); f[1] = b2f(w.y); f[2] = b2f(w.z); f[3] = b2f(w.w);
  }
}
__device__ __forceinline__ void ld8(const void* p, int i, int mode, float* f) {
  if (mode) {
    const float4* q = (const float4*)((const float*)p + i);
    float4 a = q[0], b = q[1];
    f[0] = a.x; f[1] = a.y; f[2] = a.z; f[3] = a.w;
    f[4] = b.x; f[5] = b.y; f[6] = b.z; f[7] = b.w;
  } else {
    uint4 w = *(const uint4*)((const u16*)p + i);
    b2x2(w.x, f[0], f[1]); b2x2(w.y, f[2], f[3]);
    b2x2(w.z, f[4], f[5]); b2x2(w.w, f[6], f[7]);
  }
}

// ---- dtype detector: bf16 N(0,1) exponents cluster near 127; fp32 low-half
// u16s decode to uniform-random exponents -> mostly implausible. ----
__global__ __launch_bounds__(256) void detect_kernel(const void* x, int* flag) {
  __shared__ int cnt;
  if (threadIdx.x == 0) cnt = 0;
  __syncthreads();
  const u16* p = (const u16*)x;
  u16 v = p[threadIdx.x * 2];
  int e = (v >> 7) & 0xff;
  int bad = (e > 157) || (e != 0 && e < 97);
  if (bad) atomicAdd(&cnt, 1);
  __syncthreads();
  if (threadIdx.x == 0) *flag = (cnt > 16) ? 1 : 0;
}

// ---- block-wide twin reduction ----
__device__ __forceinline__ void block_reduce2(float& a, float& b, float* sc, int nw) {
  int lane = threadIdx.x & 63, wid = threadIdx.x >> 6;
#pragma unroll
  for (int o = 32; o > 0; o >>= 1) {
    a += __shfl_down(a, o, 64);
    b += __shfl_down(b, o, 64);
  }
  if (lane == 0) { sc[wid * 2] = a; sc[wid * 2 + 1] = b; }
  __syncthreads();
  float ta = 0.f, tb = 0.f;
  for (int i = 0; i < nw; ++i) { ta += sc[i * 2]; tb += sc[i * 2 + 1]; }
  a = ta; b = tb;
}

// ---- patch embed ----
__global__ __launch_bounds__(256) void patch_embed(const void* __restrict__ x,
    const void* __restrict__ pw, const void* __restrict__ pb,
    const int* __restrict__ flag, float* __restrict__ h) {
  __shared__ float xs[256];
  int mode = *flag;
  int blk = blockIdx.x;
  int b = blk >> 8, rem = blk & 255, ph = rem >> 5, pwd = rem & 31;
  int t = threadIdx.x, p = t >> 4, q = t & 15;
  xs[t] = ldone(x, ((b * 128) + ph * 16 + p) * 512 + pwd * 16 + q, mode);
  __syncthreads();
  size_t obase = ((size_t)(b * LL) + ph * 32 + pwd) * DM;
  for (int dd = 0; dd < 2; ++dd) {
    int d = t + dd * 256;
    float s = 0.f;
    for (int i = 0; i < 256; i += 8) {
      float wf[8]; ld8(pw, d * 256 + i, mode, wf);
#pragma unroll
      for (int j = 0; j < 8; ++j) s = fmaf(xs[i + j], wf[j], s);
    }
    h[obase + d] = s + ldone(pb, d, mode);
  }
}

// ---- LayerNorm over last dim (512) ----
__global__ __launch_bounds__(256) void ln_kernel(const float* __restrict__ x,
    const void* __restrict__ w, const void* __restrict__ bias, int wOff,
    const int* __restrict__ flag, float* __restrict__ y) {
  __shared__ float sc[8];
  int mode = *flag;
  int row = blockIdx.x, t = threadIdx.x;
  const float* xr = x + (size_t)row * DM;
  float v0 = xr[t], v1 = xr[t + 256];
  float s = v0 + v1, ss = v0 * v0 + v1 * v1;
  block_reduce2(s, ss, sc, 4);
  float mean = s * (1.f / 512.f);
  float var = ss * (1.f / 512.f) - mean * mean;
  float inv = rsqrtf(var + 1e-5f);
  float* yr = y + (size_t)row * DM;
  yr[t] = (v0 - mean) * inv * ldone(w, wOff + t, mode) + ldone(bias, wOff + t, mode);
  yr[t + 256] = (v1 - mean) * inv * ldone(w, wOff + t + 256, mode) +
                ldone(bias, wOff + t + 256, mode);
}

// ---- C(M,N) = X(M,K) fp32 @ W(N,K)^T ; optional += into C ----
__global__ __launch_bounds__(256) void gemm_xwT(const float* __restrict__ X,
    const void* __restrict__ W, int wOff, const int* __restrict__ flag,
    float* __restrict__ C, int M, int N, int K, int addFlag) {
  __shared__ __align__(16) float As[16][68];
  __shared__ __align__(16) float Bs[16][68];
  int mode = *flag;
  int bm = blockIdx.y * 64, bn = blockIdx.x * 64;
  int t = threadIdx.x, tx = t & 15, ty = t >> 4;
  int lr = t >> 2, lq = t & 3;
  float acc[4][4] = {};
  for (int k0 = 0; k0 < K; k0 += 16) {
    float4 av = *(const float4*)(X + (size_t)(bm + lr) * K + k0 + lq * 4);
    float wf[4]; ld4(W, wOff + (bn + lr) * K + k0 + lq * 4, mode, wf);
    As[lq * 4 + 0][lr] = av.x; As[lq * 4 + 1][lr] = av.y;
    As[lq * 4 + 2][lr] = av.z; As[lq * 4 + 3][lr] = av.w;
    Bs[lq * 4 + 0][lr] = wf[0]; Bs[lq * 4 + 1][lr] = wf[1];
    Bs[lq * 4 + 2][lr] = wf[2]; Bs[lq * 4 + 3][lr] = wf[3];
    __syncthreads();
#pragma unroll
    for (int kk = 0; kk < 16; ++kk) {
      float4 a4 = *(const float4*)&As[kk][ty * 4];
      float4 b4 = *(const float4*)&Bs[kk][tx * 4];
      float ar[4] = {a4.x, a4.y, a4.z, a4.w};
      float br[4] = {b4.x, b4.y, b4.z, b4.w};
#pragma unroll
      for (int i = 0; i < 4; ++i)
#pragma unroll
        for (int j = 0; j < 4; ++j)
          acc[i][j] = fmaf(ar[i], br[j], acc[i][j]);
    }
    __syncthreads();
  }
#pragma unroll
  for (int i = 0; i < 4; ++i) {
    float* cp = C + (size_t)(bm + ty * 4 + i) * N + bn + tx * 4;
    if (addFlag) {
      float4 old = *(const float4*)cp;
      old.x += acc[i][0]; old.y += acc[i][1];
      old.z += acc[i][2]; old.w += acc[i][3];
      *(float4*)cp = old;
    } else {
      float4 vv = {acc[i][0], acc[i][1], acc[i][2], acc[i][3]};
      *(float4*)cp = vv;
    }
  }
}

// ---- depthwise causal conv (K=4) + SiLU, both directions ----
__global__ __launch_bounds__(256) void conv_silu(const float* __restrict__ xz,
    const void* cwF, const void* cbF, const void* cwB, const void* cbB,
    int cwOff, int cbOff, const int* __restrict__ flag, float* __restrict__ u) {
  int mode = *flag;
  int blk = blockIdx.x;
  int dir = blk >> 10, rem = blk & 1023, b = rem >> 8, l = rem & 255;
  const void* cw = dir ? cwB : cwF;
  const void* cb = dir ? cbB : cbF;
  int t = threadIdx.x;
  size_t xbase = (size_t)(b * LL) * 2048;
  size_t ubase = (((size_t)dir * BB + b) * LL + l) * DI;
  for (int dd = 0; dd < 4; ++dd) {
    int d = t + dd * 256;
    float acc = ldone(cb, cbOff + d, mode);
#pragma unroll
    for (int k = 0; k < 4; ++k) {
      int li = l + k - 3;
      if (li >= 0) {
        int sl = dir ? (LL - 1 - li) : li;
        acc = fmaf(xz[xbase + (size_t)sl * 2048 + d], ldone(cw, cwOff + d * 4 + k, mode), acc);
      }
    }
    u[ubase + d] = silu_f(acc);
  }
}

// ---- xdbl[row, e] = sum_d u[row,d] * xw[e,d] (e<64) ----
__global__ __launch_bounds__(256) void xproj_kernel(const float* __restrict__ u,
    const void* xwF, const void* xwB, int wOff, const int* __restrict__ flag,
    float* __restrict__ xdbl) {
  __shared__ __align__(16) float us[1024];
  __shared__ float part[4][64];
  int mode = *flag;
  int blk = blockIdx.x;
  int dir = blk >> 10, rem = blk & 1023;
  const void* xw = dir ? xwB : xwF;
  const float* ur = u + ((size_t)dir * 1024 + rem) * DI;
  int t = threadIdx.x;
  *(float4*)&us[t * 4] = *(const float4*)(ur + t * 4);
  __syncthreads();
  int e = t & 63, pr = t >> 6;
  const float* up = us + pr * 256;
  float s = 0.f;
  for (int i = 0; i < 256; i += 8) {
    float wf[8]; ld8(xw, wOff + e * DI + pr * 256 + i, mode, wf);
#pragma unroll
    for (int j = 0; j < 8; ++j) s = fmaf(up[i + j], wf[j], s);
  }
  part[pr][e] = s;
  __syncthreads();
  if (t < 64)
    xdbl[((size_t)dir * 1024 + rem) * 64 + t] =
        part[0][t] + part[1][t] + part[2][t] + part[3][t];
}

// ---- dt[row, d] = softplus(dtr @ W^T + bias) ----
__global__ __launch_bounds__(256) void dt_kernel(const float* __restrict__ xdbl,
    const void* dtwF, const void* dtbF, const void* dtwB, const void* dtbB,
    int wOff, int bOff, const int* __restrict__ flag, float* __restrict__ dt) {
  __shared__ float dtr[32];
  int mode = *flag;
  int blk = blockIdx.x;
  int dir = blk >> 10, rem = blk & 1023;
  const void* dtw = dir ? dtwB : dtwF;
  const void* dtb = dir ? dtbB : dtbF;
  int t = threadIdx.x;
  const float* xrow = xdbl + ((size_t)dir * 1024 + rem) * 64;
  if (t < 32) dtr[t] = xrow[t];
  __syncthreads();
  size_t obase = ((size_t)dir * 1024 + rem) * DI;
  for (int dd = 0; dd < 4; ++dd) {
    int d = t + dd * 256;
    float s = ldone(dtb, bOff + d, mode);
#pragma unroll
    for (int i = 0; i < 32; i += 8) {
      float wf[8]; ld8(dtw, wOff + d * 32 + i, mode, wf);
#pragma unroll
      for (int j = 0; j < 8; ++j) s = fmaf(dtr[i + j], wf[j], s);
    }
    dt[obase + d] = (s > 15.f) ? s : log1pf(__expf(s));
  }
}

// ---- selective scan: thread per (dir,b,d,s); serial over L ----
__global__ __launch_bounds__(256) void scan_kernel(const float* __restrict__ dt,
    const float* __restrict__ u, const float* __restrict__ xdbl,
    const void* AlogF, const void* AlogB, const void* DF, const void* DB,
    int aOff, int dOff, const int* __restrict__ flag, float* __restrict__ y) {
  int mode = *flag;
  int blk = blockIdx.x;
  int dir = blk >> 8, rem = blk & 255, b = rem >> 6, dg = rem & 63;
  int t = threadIdx.x, s = t & 15, dl = t >> 4, d = dg * 16 + dl;
  const void* Alog = dir ? AlogB : AlogF;
  const void* Dpt = dir ? DB : DF;
  float A = -__expf(ldone(Alog, aOff + d * 16 + s, mode));
  float Dp = ldone(Dpt, dOff + d, mode);
  size_t rbase = ((size_t)dir * BB + b) * LL;
  const float* dtp = dt + rbase * DI + d;
  const float* up = u + rbase * DI + d;
  const float* xd = xdbl + rbase * 64;
  float* yp = y + rbase * DI + d;
  float hst = 0.f;
  float dtv = dtp[0], uv = up[0], Bv = xd[32 + s], Cv = xd[48 + s];
  for (int l = 0; l < LL; ++l) {
    int ln = (l + 1 < LL) ? l + 1 : l;
    float ndt = dtp[(size_t)ln * DI];
    float nu = up[(size_t)ln * DI];
    float nB = xd[ln * 64 + 32 + s];
    float nC = xd[ln * 64 + 48 + s];
    float dA = __expf(dtv * A);
    hst = fmaf(dA, hst, dtv * uv * Bv);
    float p = hst * Cv;
    p += __shfl_xor(p, 1, 64);
    p += __shfl_xor(p, 2, 64);
    p += __shfl_xor(p, 4, 64);
    p += __shfl_xor(p, 8, 64);
    if (s == 0) {
      int lo = dir ? (LL - 1 - l) : l;
      yp[(size_t)lo * DI] = p + uv * Dp;
    }
    dtv = ndt; uv = nu; Bv = nB; Cv = nC;
  }
}

// ---- yg = (y_f + y_b) * silu(z) ----
__global__ __launch_bounds__(256) void gate_kernel(const float* __restrict__ y,
    const float* __restrict__ xz, float* __restrict__ yg) {
  int idx = blockIdx.x * 256 + threadIdx.x;
  int row = idx >> 8, d4 = (idx & 255) * 4;
  const float4 yf = *(const float4*)(y + (size_t)row * DI + d4);
  const float4 yb = *(const float4*)(y + 1048576 + (size_t)row * DI + d4);
  const float4 zv = *(const float4*)(xz + (size_t)row * 2048 + 1024 + d4);
  float4 o;
  o.x = (yf.x + yb.x) * silu_f(zv.x);
  o.y = (yf.y + yb.y) * silu_f(zv.y);
  o.z = (yf.z + yb.z) * silu_f(zv.z);
  o.w = (yf.w + yb.w) * silu_f(zv.w);
  *(float4*)(yg + (size_t)row * DI + d4) = o;
}

// ---- mean over L ----
__global__ __launch_bounds__(256) void pool_kernel(const float* __restrict__ hn,
    float* __restrict__ feat) {
  int b = blockIdx.x >> 1, half = blockIdx.x & 1;
  int d = half * 256 + threadIdx.x;
  float s = 0.f;
  for (int l = 0; l < LL; ++l) s += hn[((size_t)b * LL + l) * DM + d];
  feat[b * DM + d] = s * (1.f / 256.f);
}

// ---- classifier head: LN -> fc1+relu -> fc2 ; OUTPUT IS FP32 ----
__global__ __launch_bounds__(512) void head_kernel(const float* __restrict__ feat,
    const void* lnw, const void* lnb, const void* fc1w, const void* fc1b,
    const void* fc2w, const void* fc2b, const int* __restrict__ flag,
    float* __restrict__ out) {
  __shared__ float sc[16];
  __shared__ float c[512];
  __shared__ float r[512];
  int mode = *flag;
  int b = blockIdx.x, t = threadIdx.x;
  float v = feat[b * DM + t];
  float s = v, ss = v * v;
  block_reduce2(s, ss, sc, 8);
  float mean = s * (1.f / 512.f);
  float var = ss * (1.f / 512.f) - mean * mean;
  float inv = rsqrtf(var + 1e-5f);
  c[t] = (v - mean) * inv * ldone(lnw, t, mode) + ldone(lnb, t, mode);
  __syncthreads();
  float a = ldone(fc1b, t, mode);
  for (int i = 0; i < 512; i += 8) {
    float wf[8]; ld8(fc1w, t * 512 + i, mode, wf);
#pragma unroll
    for (int j = 0; j < 8; ++j) a = fmaf(c[i + j], wf[j], a);
  }
  r[t] = fmaxf(a, 0.f);
  __syncthreads();
  if (t < 10) {
    float a2 = ldone(fc2b, t, mode);
    for (int i = 0; i < 512; ++i) a2 = fmaf(r[i], ldone(fc2w, t * 512 + i, mode), a2);
    out[b * 10 + t] = a2;
  }
}

extern "C" void kernel_launch(void* const* d_in, const int* in_sizes, int n_in,
                              void* d_out, int out_size, void* d_ws, size_t ws_size,
                              hipStream_t stream) {
  (void)in_sizes; (void)n_in; (void)out_size; (void)ws_size;
  const void* x          = d_in[0];
  const void* patch_w    = d_in[1];
  const void* patch_b    = d_in[2];
  const void* in_proj_w  = d_in[3];
  const void* conv_w_f   = d_in[4];
  const void* conv_b_f   = d_in[5];
  const void* xproj_w_f  = d_in[6];
  const void* dtproj_w_f = d_in[7];
  const void* dtproj_b_f = d_in[8];
  const void* A_log_f    = d_in[9];
  const void* D_f        = d_in[10];
  const void* conv_w_b   = d_in[11];
  const void* conv_b_b   = d_in[12];
  const void* xproj_w_b  = d_in[13];
  const void* dtproj_w_b = d_in[14];
  const void* dtproj_b_b = d_in[15];
  const void* A_log_b    = d_in[16];
  const void* D_b        = d_in[17];
  const void* out_proj_w = d_in[18];
  const void* norm_w     = d_in[19];
  const void* norm_b     = d_in[20];
  const void* normf_w    = d_in[21];
  const void* normf_b    = d_in[22];
  const void* ln_w       = d_in[23];
  const void* ln_b       = d_in[24];
  const void* fc1_w      = d_in[25];
  const void* fc1_b      = d_in[26];
  const void* fc2_w      = d_in[27];
  const void* fc2_b      = d_in[28];

  float* ws   = (float*)d_ws;
  float* hbuf = ws;                 // 524288
  float* xn   = ws + 524288;        // 524288
  float* xz   = ws + 1048576;       // 2097152
  float* ubuf = ws + 3145728;       // 2097152 (2 dirs)
  float* xdbl = ws + 5242880;       // 131072  (2 dirs)
  float* dtb  = ws + 5373952;       // 2097152 (2 dirs)
  float* ybuf = ws + 7471104;       // 2097152 (2 dirs)
  float* yg   = ws + 9568256;       // 1048576
  float* hn   = ws + 10616832;      // 524288
  float* feat = ws + 11141120;      // 2048
  int*   flag = (int*)(ws + 11143168);

  detect_kernel<<<1, 256, 0, stream>>>(x, flag);
  patch_embed<<<1024, 256, 0, stream>>>(x, patch_w, patch_b, flag, hbuf);
  for (int i = 0; i < 4; ++i) {
    ln_kernel<<<1024, 256, 0, stream>>>(hbuf, norm_w, norm_b, i * 512, flag, xn);
    gemm_xwT<<<dim3(32, 16), 256, 0, stream>>>(
        xn, in_proj_w, i * 1048576, flag, xz, 1024, 2048, 512, 0);
    conv_silu<<<2048, 256, 0, stream>>>(xz, conv_w_f, conv_b_f, conv_w_b, conv_b_b,
                                        i * 4096, i * 1024, flag, ubuf);
    xproj_kernel<<<2048, 256, 0, stream>>>(ubuf, xproj_w_f, xproj_w_b, i * 65536,
                                           flag, xdbl);
    dt_kernel<<<2048, 256, 0, stream>>>(xdbl, dtproj_w_f, dtproj_b_f, dtproj_w_b,
                                        dtproj_b_b, i * 32768, i * 1024, flag, dtb);
    scan_kernel<<<512, 256, 0, stream>>>(dtb, ubuf, xdbl, A_log_f, A_log_b, D_f, D_b,
                                         i * 16384, i * 1024, flag, ybuf);
    gate_kernel<<<1024, 256, 0, stream>>>(ybuf, xz, yg);
    gemm_xwT<<<dim3(8, 16), 256, 0, stream>>>(
        yg, out_proj_w, i * 524288, flag, hbuf, 1024, 512, 1024, 1);
  }
  ln_kernel<<<1024, 256, 0, stream>>>(hbuf, normf_w, normf_b, 0, flag, hn);
  pool_kernel<<<8, 256, 0, stream>>>(hn, feat);
  head_kernel<<<4, 512, 0, stream>>>(feat, ln_w, ln_b, fc1_w, fc1_b, fc2_w, fc2_b,
                                     flag, (float*)d_out);
}

// Round 4
// 996.750 us; speedup vs baseline: 1.4212x; 1.4212x over previous
//
#include <hip/hip_runtime.h>

// AudioMamba forward, fp32, fused. Inputs fp32, output fp32.
// B=4, L=256, D_MODEL=512, D_INNER=1024, S=16, R=32, DEPTH=4.
// Launches: patch, 4x(gemm1_ln, fused_cxd, scan_chunked, gemm2_gate), lnF, head_pool.

#define BB 4
#define LL 256
#define DM 512
#define DI 1024

__device__ __forceinline__ float silu_f(float x){ return x/(1.f+__expf(-x)); }

__device__ __forceinline__ void block_reduce2(float& a, float& b, float* sc, int nw){
  int lane = threadIdx.x & 63, wid = threadIdx.x >> 6;
#pragma unroll
  for (int o = 32; o > 0; o >>= 1){
    a += __shfl_down(a, o, 64);
    b += __shfl_down(b, o, 64);
  }
  if (lane == 0){ sc[wid*2] = a; sc[wid*2+1] = b; }
  __syncthreads();
  float ta = 0.f, tb = 0.f;
  for (int i = 0; i < nw; ++i){ ta += sc[i*2]; tb += sc[i*2+1]; }
  a = ta; b = tb;
}

// ---- patch embed: 128 blocks (b4, ph8, pg4); each block does 8 tokens ----
__global__ __launch_bounds__(256) void patch_embed(const float* __restrict__ x,
    const float* __restrict__ pw, const float* __restrict__ pb, float* __restrict__ h){
  __shared__ float xs[8*256];
  int blk = blockIdx.x;
  int b = blk >> 5, ph = (blk >> 2) & 7, pg = blk & 3;
  int t = threadIdx.x;
  for (int idx = t; idx < 2048; idx += 256){
    int j = idx >> 8, pix = idx & 255, p = pix >> 4, q = pix & 15;
    xs[idx] = x[(size_t)(b*128 + ph*16 + p)*512 + pg*128 + j*16 + q];
  }
  __syncthreads();
  for (int dd = 0; dd < 2; ++dd){
    int d = t + dd*256;
    float acc[8] = {};
    const float* wr = pw + (size_t)d*256;
    for (int i = 0; i < 256; i += 8){
      float4 w0 = *(const float4*)(wr + i);
      float4 w1 = *(const float4*)(wr + i + 4);
      float wf[8] = {w0.x,w0.y,w0.z,w0.w,w1.x,w1.y,w1.z,w1.w};
#pragma unroll
      for (int j = 0; j < 8; ++j){
#pragma unroll
        for (int jj = 0; jj < 8; ++jj)
          acc[j] = fmaf(xs[j*256 + i + jj], wf[jj], acc[j]);
      }
    }
    float bias = pb[d];
#pragma unroll
    for (int j = 0; j < 8; ++j)
      h[(size_t)(b*256 + ph*32 + pg*8 + j)*512 + d] = acc[j] + bias;
  }
}

// ---- in_proj GEMM with LN fused into the A-operand load ----
// C(1024,2048) = LN(X)(1024,512) @ W(2048,512)^T
__global__ __launch_bounds__(256) void gemm1_ln(const float* __restrict__ X,
    const float* __restrict__ lnw, const float* __restrict__ lnb, int lnOff,
    const float* __restrict__ W, int wOff, float* __restrict__ C){
  __shared__ __align__(16) float As[16][68];
  __shared__ __align__(16) float Bs[16][68];
  __shared__ float rmean[64], rrstd[64];
  int bm = blockIdx.y * 64, bn = blockIdx.x * 64;
  int t = threadIdx.x;
  int lr = t >> 2, lq = t & 3;
  { // row stats for the 64 A-rows of this block
    const float* xr = X + (size_t)(bm + lr)*512 + lq*128;
    float s = 0.f, ss = 0.f;
    for (int i = 0; i < 128; i += 4){
      float4 v = *(const float4*)(xr + i);
      s  += v.x + v.y + v.z + v.w;
      ss += v.x*v.x + v.y*v.y + v.z*v.z + v.w*v.w;
    }
    s += __shfl_xor(s, 1, 64); ss += __shfl_xor(ss, 1, 64);
    s += __shfl_xor(s, 2, 64); ss += __shfl_xor(ss, 2, 64);
    if (lq == 0){
      float m = s * (1.f/512.f);
      float var = ss * (1.f/512.f) - m*m;
      rmean[lr] = m; rrstd[lr] = rsqrtf(var + 1e-5f);
    }
  }
  __syncthreads();
  int tx = t & 15, ty = t >> 4;
  float acc[4][4] = {};
  for (int k0 = 0; k0 < 512; k0 += 16){
    int kk4 = k0 + lq*4;
    float4 av = *(const float4*)(X + (size_t)(bm + lr)*512 + kk4);
    float4 wv = *(const float4*)(lnw + lnOff + kk4);
    float4 bv = *(const float4*)(lnb + lnOff + kk4);
    float4 wb = *(const float4*)(W + wOff + (size_t)(bn + lr)*512 + kk4);
    float mm = rmean[lr], rr = rrstd[lr];
    As[lq*4+0][lr] = (av.x - mm)*rr*wv.x + bv.x;
    As[lq*4+1][lr] = (av.y - mm)*rr*wv.y + bv.y;
    As[lq*4+2][lr] = (av.z - mm)*rr*wv.z + bv.z;
    As[lq*4+3][lr] = (av.w - mm)*rr*wv.w + bv.w;
    Bs[lq*4+0][lr] = wb.x; Bs[lq*4+1][lr] = wb.y;
    Bs[lq*4+2][lr] = wb.z; Bs[lq*4+3][lr] = wb.w;
    __syncthreads();
#pragma unroll
    for (int kk = 0; kk < 16; ++kk){
      float4 a4 = *(const float4*)&As[kk][ty*4];
      float4 b4 = *(const float4*)&Bs[kk][tx*4];
      float ar[4] = {a4.x, a4.y, a4.z, a4.w};
      float br[4] = {b4.x, b4.y, b4.z, b4.w};
#pragma unroll
      for (int i = 0; i < 4; ++i)
#pragma unroll
        for (int j = 0; j < 4; ++j)
          acc[i][j] = fmaf(ar[i], br[j], acc[i][j]);
    }
    __syncthreads();
  }
#pragma unroll
  for (int i = 0; i < 4; ++i){
    float4 vv = {acc[i][0], acc[i][1], acc[i][2], acc[i][3]};
    *(float4*)(C + (size_t)(bm + ty*4 + i)*2048 + bn + tx*4) = vv;
  }
}

// ---- fused conv+silu -> xproj -> dtproj+softplus; block per (dir,b, 4 l's) ----
__global__ __launch_bounds__(256) void fused_cxd(const float* __restrict__ xz,
    const float* __restrict__ cwF, const float* __restrict__ cbF,
    const float* __restrict__ cwB, const float* __restrict__ cbB,
    const float* __restrict__ xwF, const float* __restrict__ xwB,
    const float* __restrict__ dtwF, const float* __restrict__ dtbF,
    const float* __restrict__ dtwB, const float* __restrict__ dtbB,
    int cwOff, int cbOff, int xwOff, int dtwOff, int dtbOff,
    float* __restrict__ u, float* __restrict__ xdbl, float* __restrict__ dtout){
  __shared__ float us[4*1024];
  __shared__ float part[16*64];
  __shared__ float dtr[4*32];
  int blk = blockIdx.x;
  int dir = blk >> 8, rem = blk & 255, b = rem >> 6, lg = rem & 63;
  int l0 = lg*4;
  const float* cw  = dir ? cwB  : cwF;
  const float* cb  = dir ? cbB  : cbF;
  const float* xw  = dir ? xwB  : xwF;
  const float* dtw = dir ? dtwB : dtwF;
  const float* dtb = dir ? dtbB : dtbF;
  int t = threadIdx.x;
  int rbase = (dir*BB + b)*LL;
  // conv(K=4 causal, depthwise) + silu for 4 rows
  for (int dd = 0; dd < 4; ++dd){
    int d = t + dd*256;
    float4 w4 = *(const float4*)(cw + cwOff + d*4);
    float wf[4] = {w4.x, w4.y, w4.z, w4.w};
    float bias = cb[cbOff + d];
#pragma unroll
    for (int r = 0; r < 4; ++r){
      int l = l0 + r;
      float acc = bias;
#pragma unroll
      for (int k = 0; k < 4; ++k){
        int li = l + k - 3;
        if (li >= 0){
          int sl = dir ? (LL-1-li) : li;
          acc = fmaf(xz[(size_t)(b*LL + sl)*2048 + d], wf[k], acc);
        }
      }
      float uval = silu_f(acc);
      us[r*1024 + d] = uval;
      u[(size_t)(rbase + l)*DI + d] = uval;
    }
  }
  __syncthreads();
  // xproj: e = output idx (64), pr = quarter of the 1024-dot
  {
    int e = t & 63, pr = t >> 6;
    float accs[4] = {};
    const float* wr = xw + xwOff + (size_t)e*1024 + pr*256;
    for (int i = 0; i < 256; i += 8){
      float4 w0 = *(const float4*)(wr + i);
      float4 w1 = *(const float4*)(wr + i + 4);
      float wf[8] = {w0.x,w0.y,w0.z,w0.w,w1.x,w1.y,w1.z,w1.w};
#pragma unroll
      for (int r = 0; r < 4; ++r){
        const float* ub = us + r*1024 + pr*256 + i;
#pragma unroll
        for (int j = 0; j < 8; ++j)
          accs[r] = fmaf(ub[j], wf[j], accs[r]);
      }
    }
#pragma unroll
    for (int r = 0; r < 4; ++r) part[(pr*4 + r)*64 + e] = accs[r];
  }
  __syncthreads();
  {
    int r = t >> 6, e = t & 63;
    float v = part[(0*4+r)*64+e] + part[(1*4+r)*64+e] +
              part[(2*4+r)*64+e] + part[(3*4+r)*64+e];
    xdbl[(size_t)(rbase + l0 + r)*64 + e] = v;
    if (e < 32) dtr[r*32 + e] = v;
  }
  __syncthreads();
  // dtproj + softplus
  for (int dd = 0; dd < 4; ++dd){
    int d = t + dd*256;
    float bias = dtb[dtbOff + d];
    float accs[4] = {bias, bias, bias, bias};
    const float* wr = dtw + dtwOff + (size_t)d*32;
    for (int i = 0; i < 32; i += 8){
      float4 w0 = *(const float4*)(wr + i);
      float4 w1 = *(const float4*)(wr + i + 4);
      float wf[8] = {w0.x,w0.y,w0.z,w0.w,w1.x,w1.y,w1.z,w1.w};
#pragma unroll
      for (int r = 0; r < 4; ++r)
#pragma unroll
        for (int j = 0; j < 8; ++j)
          accs[r] = fmaf(dtr[r*32 + i + j], wf[j], accs[r]);
    }
#pragma unroll
    for (int r = 0; r < 4; ++r){
      float sv = accs[r];
      dtout[(size_t)(rbase + l0 + r)*DI + d] = (sv > 15.f) ? sv : log1pf(__expf(sv));
    }
  }
}

// ---- chunked selective scan: block per (dir,b,d); threads (c16, s16) ----
__global__ __launch_bounds__(256) void scan_chunked(const float* __restrict__ dt,
    const float* __restrict__ u, const float* __restrict__ xd,
    const float* __restrict__ AlogF, const float* __restrict__ AlogB,
    const float* __restrict__ DF, const float* __restrict__ DB,
    int aOff, int dOff, float* __restrict__ y){
  __shared__ float cA[16][17], cB[16][17], hin[16][17];
  int blk = blockIdx.x;
  int dir = blk >> 12, rem = blk & 4095, b = rem >> 10, d = rem & 1023;
  int t = threadIdx.x, s = t & 15, c = t >> 4;
  const float* Alog = dir ? AlogB : AlogF;
  const float* Dpt  = dir ? DB : DF;
  float A  = -__expf(Alog[aOff + d*16 + s]);
  float Dp = Dpt[dOff + d];
  int rbase = (dir*BB + b)*LL;
  const float* dtp = dt + (size_t)rbase*DI + d;
  const float* up  = u  + (size_t)rbase*DI + d;
  const float* xr  = xd + (size_t)rbase*64;
  int l0 = c*16;
  float uv[16], ab[16], bb[16];
  {
    float dtv[16], Bv[16];
#pragma unroll
    for (int i = 0; i < 16; ++i){
      dtv[i] = dtp[(size_t)(l0+i)*DI];
      uv[i]  = up[(size_t)(l0+i)*DI];
      Bv[i]  = xr[(l0+i)*64 + 32 + s];
    }
    float Ap = 1.f, hh = 0.f;
#pragma unroll
    for (int i = 0; i < 16; ++i){
      float a  = __expf(dtv[i]*A);
      float bv = dtv[i]*uv[i]*Bv[i];
      ab[i] = a; bb[i] = bv;
      Ap *= a;
      hh = fmaf(a, hh, bv);
    }
    cA[c][s] = Ap; cB[c][s] = hh;
  }
  float Cv[16];
#pragma unroll
  for (int i = 0; i < 16; ++i) Cv[i] = xr[(l0+i)*64 + 48 + s];
  __syncthreads();
  if (t < 16){
    float run = 0.f;
#pragma unroll
    for (int cc = 0; cc < 16; ++cc){
      hin[cc][t] = run;
      run = fmaf(cA[cc][t], run, cB[cc][t]);
    }
  }
  __syncthreads();
  float hh = hin[c][s];
  float* yp = y + (size_t)rbase*DI + d;
#pragma unroll
  for (int i = 0; i < 16; ++i){
    hh = fmaf(ab[i], hh, bb[i]);
    float p = hh * Cv[i];
    p += __shfl_xor(p, 1, 64);
    p += __shfl_xor(p, 2, 64);
    p += __shfl_xor(p, 4, 64);
    p += __shfl_xor(p, 8, 64);
    if (s == 0){
      int l = l0 + i;
      int lo = dir ? (LL-1-l) : l;
      yp[(size_t)lo*DI] = p + uv[i]*Dp;
    }
  }
}

// ---- out_proj GEMM with gate fused into the A-operand load; C += A@W^T ----
// A[row,k] = (yf[row,k] + yb[row,k]) * silu(z[row,k]); M=1024, N=512, K=1024
__global__ __launch_bounds__(256) void gemm2_gate(const float* __restrict__ yb2,
    const float* __restrict__ xz, const float* __restrict__ W, int wOff,
    float* __restrict__ C){
  __shared__ __align__(16) float As[16][68];
  __shared__ __align__(16) float Bs[16][68];
  int bm = blockIdx.y*64, bn = blockIdx.x*64;
  int t = threadIdx.x, tx = t & 15, ty = t >> 4;
  int lr = t >> 2, lq = t & 3;
  float acc[4][4] = {};
  for (int k0 = 0; k0 < 1024; k0 += 16){
    int row = bm + lr, kk4 = k0 + lq*4;
    float4 yf  = *(const float4*)(yb2 + (size_t)row*DI + kk4);
    float4 ybk = *(const float4*)(yb2 + (size_t)(1024 + row)*DI + kk4);
    float4 zv  = *(const float4*)(xz + (size_t)row*2048 + 1024 + kk4);
    float4 wb  = *(const float4*)(W + wOff + (size_t)(bn + lr)*1024 + kk4);
    As[lq*4+0][lr] = (yf.x + ybk.x)*silu_f(zv.x);
    As[lq*4+1][lr] = (yf.y + ybk.y)*silu_f(zv.y);
    As[lq*4+2][lr] = (yf.z + ybk.z)*silu_f(zv.z);
    As[lq*4+3][lr] = (yf.w + ybk.w)*silu_f(zv.w);
    Bs[lq*4+0][lr] = wb.x; Bs[lq*4+1][lr] = wb.y;
    Bs[lq*4+2][lr] = wb.z; Bs[lq*4+3][lr] = wb.w;
    __syncthreads();
#pragma unroll
    for (int kk = 0; kk < 16; ++kk){
      float4 a4 = *(const float4*)&As[kk][ty*4];
      float4 b4 = *(const float4*)&Bs[kk][tx*4];
      float ar[4] = {a4.x, a4.y, a4.z, a4.w};
      float br[4] = {b4.x, b4.y, b4.z, b4.w};
#pragma unroll
      for (int i = 0; i < 4; ++i)
#pragma unroll
        for (int j = 0; j < 4; ++j)
          acc[i][j] = fmaf(ar[i], br[j], acc[i][j]);
    }
    __syncthreads();
  }
#pragma unroll
  for (int i = 0; i < 4; ++i){
    float* cp = C + (size_t)(bm + ty*4 + i)*512 + bn + tx*4;
    float4 old = *(const float4*)cp;
    old.x += acc[i][0]; old.y += acc[i][1];
    old.z += acc[i][2]; old.w += acc[i][3];
    *(float4*)cp = old;
  }
}

// ---- final LayerNorm (per token row) ----
__global__ __launch_bounds__(256) void ln_kernel(const float* __restrict__ x,
    const float* __restrict__ w, const float* __restrict__ bias,
    float* __restrict__ y){
  __shared__ float sc[8];
  int row = blockIdx.x, t = threadIdx.x;
  const float* xr = x + (size_t)row*DM;
  float v0 = xr[t], v1 = xr[t + 256];
  float s = v0 + v1, ss = v0*v0 + v1*v1;
  block_reduce2(s, ss, sc, 4);
  float mean = s * (1.f/512.f);
  float var = ss * (1.f/512.f) - mean*mean;
  float inv = rsqrtf(var + 1e-5f);
  float* yr = y + (size_t)row*DM;
  yr[t]       = (v0 - mean)*inv*w[t]       + bias[t];
  yr[t + 256] = (v1 - mean)*inv*w[t + 256] + bias[t + 256];
}

// ---- pool (mean over L) + LN + fc1/relu + fc2; block per batch ----
__global__ __launch_bounds__(512) void head_pool(const float* __restrict__ hn,
    const float* __restrict__ lnw, const float* __restrict__ lnb,
    const float* __restrict__ fc1w, const float* __restrict__ fc1b,
    const float* __restrict__ fc2w, const float* __restrict__ fc2b,
    float* __restrict__ out){
  __shared__ float sc[16];
  __shared__ float cbuf[512];
  __shared__ float rbuf[512];
  int b = blockIdx.x, t = threadIdx.x;
  float v = 0.f;
  for (int l = 0; l < 256; ++l) v += hn[(size_t)(b*256 + l)*512 + t];
  v *= (1.f/256.f);
  float s = v, ss = v*v;
  block_reduce2(s, ss, sc, 8);
  float mean = s * (1.f/512.f);
  float var = ss * (1.f/512.f) - mean*mean;
  float inv = rsqrtf(var + 1e-5f);
  cbuf[t] = (v - mean)*inv*lnw[t] + lnb[t];
  __syncthreads();
  float a = fc1b[t];
  const float* w1 = fc1w + (size_t)t*512;
  for (int i = 0; i < 512; i += 8){
    float4 w0 = *(const float4*)(w1 + i);
    float4 w4 = *(const float4*)(w1 + i + 4);
    float wf[8] = {w0.x,w0.y,w0.z,w0.w,w4.x,w4.y,w4.z,w4.w};
#pragma unroll
    for (int j = 0; j < 8; ++j) a = fmaf(cbuf[i + j], wf[j], a);
  }
  rbuf[t] = fmaxf(a, 0.f);
  __syncthreads();
  if (t < 10){
    float a2 = fc2b[t];
    const float* w2 = fc2w + (size_t)t*512;
    for (int i = 0; i < 512; ++i) a2 = fmaf(rbuf[i], w2[i], a2);
    out[b*10 + t] = a2;
  }
}

extern "C" void kernel_launch(void* const* d_in, const int* in_sizes, int n_in,
                              void* d_out, int out_size, void* d_ws, size_t ws_size,
                              hipStream_t stream) {
  (void)in_sizes; (void)n_in; (void)out_size; (void)ws_size;
  const float* x          = (const float*)d_in[0];
  const float* patch_w    = (const float*)d_in[1];
  const float* patch_b    = (const float*)d_in[2];
  const float* in_proj_w  = (const float*)d_in[3];
  const float* conv_w_f   = (const float*)d_in[4];
  const float* conv_b_f   = (const float*)d_in[5];
  const float* xproj_w_f  = (const float*)d_in[6];
  const float* dtproj_w_f = (const float*)d_in[7];
  const float* dtproj_b_f = (const float*)d_in[8];
  const float* A_log_f    = (const float*)d_in[9];
  const float* D_f        = (const float*)d_in[10];
  const float* conv_w_b   = (const float*)d_in[11];
  const float* conv_b_b   = (const float*)d_in[12];
  const float* xproj_w_b  = (const float*)d_in[13];
  const float* dtproj_w_b = (const float*)d_in[14];
  const float* dtproj_b_b = (const float*)d_in[15];
  const float* A_log_b    = (const float*)d_in[16];
  const float* D_b        = (const float*)d_in[17];
  const float* out_proj_w = (const float*)d_in[18];
  const float* norm_w     = (const float*)d_in[19];
  const float* norm_b     = (const float*)d_in[20];
  const float* normf_w    = (const float*)d_in[21];
  const float* normf_b    = (const float*)d_in[22];
  const float* ln_w       = (const float*)d_in[23];
  const float* ln_b       = (const float*)d_in[24];
  const float* fc1_w      = (const float*)d_in[25];
  const float* fc1_b      = (const float*)d_in[26];
  const float* fc2_w      = (const float*)d_in[27];
  const float* fc2_b      = (const float*)d_in[28];

  float* ws   = (float*)d_ws;
  float* hbuf = ws;                 // 524288
  float* xz   = ws + 524288;        // 2097152
  float* ubuf = ws + 2621440;       // 2097152 (2 dirs)
  float* xdbl = ws + 4718592;       // 131072  (2 dirs)
  float* dtb  = ws + 4849664;       // 2097152 (2 dirs)
  float* ybuf = ws + 6946816;       // 2097152 (2 dirs)
  float* hn   = ws + 9043968;       // 524288

  patch_embed<<<128, 256, 0, stream>>>(x, patch_w, patch_b, hbuf);
  for (int i = 0; i < 4; ++i){
    gemm1_ln<<<dim3(32, 16), 256, 0, stream>>>(
        hbuf, norm_w, norm_b, i*512, in_proj_w, i*1048576, xz);
    fused_cxd<<<512, 256, 0, stream>>>(
        xz, conv_w_f, conv_b_f, conv_w_b, conv_b_b, xproj_w_f, xproj_w_b,
        dtproj_w_f, dtproj_b_f, dtproj_w_b, dtproj_b_b,
        i*4096, i*1024, i*65536, i*32768, i*1024, ubuf, xdbl, dtb);
    scan_chunked<<<8192, 256, 0, stream>>>(
        dtb, ubuf, xdbl, A_log_f, A_log_b, D_f, D_b, i*16384, i*1024, ybuf);
    gemm2_gate<<<dim3(8, 16), 256, 0, stream>>>(
        ybuf, xz, out_proj_w, i*524288, hbuf);
  }
  ln_kernel<<<1024, 256, 0, stream>>>(hbuf, normf_w, normf_b, hn);
  head_pool<<<4, 512, 0, stream>>>(hn, ln_w, ln_b, fc1_w, fc1_b, fc2_w, fc2_b,
                                   (float*)d_out);
}